// Round 8
// baseline (116.199 us; speedup 1.0000x reference)
//
#include <hip/hip_runtime.h>
#include <hip/hip_fp16.h>

// Problem constants (fixed by the reference setup)
constexpr int N = 4096;
constexpr int D = 512;
constexpr int NT = 32;                   // 4096 / 128 tile-rows
constexpr int NBLK = NT * (NT + 1) / 2;  // 528 upper-triangle tiles
constexpr float SENT = -1e30f;           // sentinel (invalid sites / empty slots)

typedef _Float16 f16x8 __attribute__((ext_vector_type(8)));
typedef float f32x4 __attribute__((ext_vector_type(4)));

// raw barrier / fine-grained vmcnt (AITER-style pipeline)
#define BAR() asm volatile("s_barrier" ::: "memory")
#define WAITV8() asm volatile("s_waitcnt vmcnt(8)" ::: "memory")
#define WAITV0() asm volatile("s_waitcnt vmcnt(0)" ::: "memory")

// async 16B/lane global->LDS (wave-uniform LDS base + lane*16)
__device__ __forceinline__ void load_lds16(const _Float16* g, _Float16* l) {
  __builtin_amdgcn_global_load_lds(
      (const __attribute__((address_space(1))) void*)g,
      (__attribute__((address_space(3))) void*)l, 16, 0, 0);
}

// branchless sorted-desc top-10 insert
__device__ __forceinline__ void ins10(float (&t)[10], float v) {
#pragma unroll
  for (int k = 9; k > 0; k--) t[k] = fmaxf(t[k], fminf(v, t[k - 1]));
  t[0] = fmaxf(t[0], v);
}

// butterfly merge of per-lane sorted-10 lists across the 64-lane wave.
// At each offset, partner subtrees are disjoint -> no duplicate insertion.
__device__ __forceinline__ void wave_merge10(float (&t)[10]) {
#pragma unroll
  for (int ofs = 1; ofs < 64; ofs <<= 1) {
    float o[10];
#pragma unroll
    for (int k = 0; k < 10; k++) o[k] = __shfl_xor(t[k], ofs);
#pragma unroll
    for (int k = 0; k < 10; k++) ins10(t, o[k]);
  }
}

// ws layout:
//   ws+0       f32 blk_sumv[528]; f32 blk_sump[528];
//              u32 blk_cntv[528]; u32 blk_cntp[528]; u32 blk_zero[528]
//   ws+10560   f32 top10g[528*10]
//   ws+31680   u32 done            (zeroed by prep)
//   ws+31744   f16 Xh[N*D]
constexpr int TOP10_OFF = 10560;
constexpr int DONE_OFF = 31680;
constexpr int XH_OFF = 31744;

// ---------------- K0: fp32 -> f16 convert (+ zero done ctr) ----------------
__global__ void prep_kernel(const float4* __restrict__ X4,
                            ushort4* __restrict__ Xh4,
                            unsigned* __restrict__ done) {
  int gid = blockIdx.x * 256 + threadIdx.x;  // grid exactly N*D/4 threads
  if (gid == 0) *done = 0u;
  float4 v = X4[gid];
  ushort4 o;
  o.x = __half_as_ushort(__float2half_rn(v.x));
  o.y = __half_as_ushort(__float2half_rn(v.y));
  o.z = __half_as_ushort(__float2half_rn(v.z));
  o.w = __half_as_ushort(__float2half_rn(v.w));
  Xh4[gid] = o;
}

// ---------------- K1: tiled X*X^T + fused loss + top-10 + last-block finalize ----------------
__global__ __launch_bounds__(256, 2) void gemm_stats_kernel(
    const _Float16* __restrict__ Xh, const int* __restrict__ tgt,
    float* __restrict__ slots, float* __restrict__ top10g,
    unsigned* __restrict__ done, float* __restrict__ out) {
  float* blk_sumv = slots;
  float* blk_sump = slots + NBLK;
  unsigned* blk_cntv = (unsigned*)(slots + 2 * NBLK);
  unsigned* blk_cntp = (unsigned*)(slots + 3 * NBLK);
  unsigned* blk_zero = (unsigned*)(slots + 4 * NBLK);

  __shared__ _Float16 As[2 * 128 * 64];  // 32 KB (double-buffered)
  __shared__ _Float16 Bs[2 * 128 * 64];  // 32 KB
  __shared__ int tA[128], tB[128];
  __shared__ float redf[2][4];
  __shared__ unsigned redu[3][4];
  __shared__ float wt[4][10];   // per-wave top-10 lists
  __shared__ int lastFlag;

  int tid = threadIdx.x;

  // decode upper-triangle tile (br <= bc)
  int id = blockIdx.x, br = 0;
  while (id >= (NT - br)) { id -= (NT - br); br++; }
  int bc = br + id;

  if (tid < 128) tA[tid] = tgt[br * 128 + tid];
  else           tB[tid - 128] = tgt[bc * 128 + (tid - 128)];

  int lane = tid & 63, wave = tid >> 6;
  int wm = (wave >> 1) << 6;
  int wn = (wave & 1) << 6;
  int lrow = lane & 15;
  int q4 = lane >> 4;  // quad 0..3
  int x7 = lrow & 7;   // swizzle key for ds_read side
  int quad4 = q4 * 4;

  // staging: issue i (0..3) covers chunks C=(i*4+wave)*64+lane;
  // row=C>>3, lds pos p=C&7 holds global chunk p^(row&7)
  int srow[4], scol[4], sdst[4];
#pragma unroll
  for (int i = 0; i < 4; i++) {
    int C = (i * 4 + wave) * 64 + lane;
    int row = C >> 3, p = C & 7;
    srow[i] = row;
    scol[i] = (p ^ (row & 7)) * 8;
    sdst[i] = (i * 4 + wave) * 512;
  }
  const _Float16* Arow = Xh + (size_t)(br * 128) * D;
  const _Float16* Brow = Xh + (size_t)(bc * 128) * D;

  auto issue = [&](int k0, int sel) {
#pragma unroll
    for (int i = 0; i < 4; i++) {
      load_lds16(Arow + srow[i] * D + k0 + scol[i], As + sel * 8192 + sdst[i]);
      load_lds16(Brow + srow[i] * D + k0 + scol[i], Bs + sel * 8192 + sdst[i]);
    }
  };

  f32x4 acc[4][4] = {};

  __syncthreads();  // tA/tB visible; drains all prior vm/lgkm
  issue(0, 0);      // cold prefetch of tile 0

#pragma unroll
  for (int it = 0; it < 8; ++it) {
    int sel = it & 1;
    if (it > 0) BAR();                // all waves done READING buffer sel^1
    if (it < 7) {
      issue((it + 1) * 64, sel ^ 1);  // prefetch next into the other buffer
      WAITV8();                       // drain only tile-it's 8 loads (~free)
    } else {
      WAITV0();
    }
    BAR();                            // all waves' tile-it deposits visible
#pragma unroll
    for (int ks = 0; ks < 64; ks += 32) {
      int c0 = ks >> 3;
      f16x8 af[4], bf[4];
#pragma unroll
      for (int mi = 0; mi < 4; mi++)
        af[mi] = *(const f16x8*)&As[sel * 8192 + (wm + mi * 16 + lrow) * 64 +
                                    ((c0 + q4) ^ x7) * 8];
#pragma unroll
      for (int ni = 0; ni < 4; ni++)
        bf[ni] = *(const f16x8*)&Bs[sel * 8192 + (wn + ni * 16 + lrow) * 64 +
                                    ((c0 + q4) ^ x7) * 8];
#pragma unroll
      for (int mi = 0; mi < 4; mi++)
#pragma unroll
        for (int ni = 0; ni < 4; ni++)
          acc[mi][ni] = __builtin_amdgcn_mfma_f32_16x16x32_f16(
              af[mi], bf[ni], acc[mi][ni], 0, 0, 0);
    }
  }

  // ---- fused epilogue: masks, hinge, stats, branchless per-thread top-10 ----
  int ti[4][4], tj[4];
#pragma unroll
  for (int ni = 0; ni < 4; ni++) tj[ni] = tB[wn + ni * 16 + lrow];
#pragma unroll
  for (int mi = 0; mi < 4; mi++)
#pragma unroll
    for (int r = 0; r < 4; r++) ti[mi][r] = tA[wm + mi * 16 + quad4 + r];

  float lsv = 0.f, lsp = 0.f;
  unsigned lcv = 0, lcp = 0, lz = 0;
  int ibase = br * 128 + wm + quad4;
  int jbase = bc * 128 + wn + lrow;

  float t10[10];
#pragma unroll
  for (int k = 0; k < 10; k++) t10[k] = SENT;

#pragma unroll
  for (int mi = 0; mi < 4; mi++)
#pragma unroll
    for (int ni = 0; ni < 4; ni++)
#pragma unroll
      for (int r = 0; r < 4; r++) {
        float s = acc[mi][ni][r];
        int i = ibase + mi * 16 + r;
        int j = jbase + ni * 16;
        bool valid = j > i;  // strict upper triangle; results doubled at the end
        bool pos = valid && (ti[mi][r] == tj[ni]);
        float t = pos ? -s : s;
        float loss = fmaxf(0.5f + t, 0.0f);
        if (valid) { lsv += s; lcv++; if (loss == 0.0f) lz++; }
        if (pos) { lsp += s; lcp++; }
        ins10(t10, valid ? loss : SENT);
      }

  // stats: wave shuffle reduce; top-10: wave butterfly merge (no barriers)
#pragma unroll
  for (int o = 32; o > 0; o >>= 1) {
    lsv += __shfl_down(lsv, o);
    lsp += __shfl_down(lsp, o);
    lcv += __shfl_down(lcv, o);
    lcp += __shfl_down(lcp, o);
    lz  += __shfl_down(lz, o);
  }
  wave_merge10(t10);
  if (lane == 0) {
    redf[0][wave] = lsv; redf[1][wave] = lsp;
    redu[0][wave] = lcv; redu[1][wave] = lcp; redu[2][wave] = lz;
#pragma unroll
    for (int k = 0; k < 10; k++) wt[wave][k] = t10[k];
  }
  __syncthreads();

  // wave 0: merge the 4 per-wave lists (lanes 0-3, 2-level butterfly), publish
  if (wave == 0) {
    float m10[10];
#pragma unroll
    for (int k = 0; k < 10; k++) m10[k] = (lane < 4) ? wt[lane][k] : SENT;
#pragma unroll
    for (int ofs = 1; ofs < 4; ofs <<= 1) {
      float o[10];
#pragma unroll
      for (int k = 0; k < 10; k++) o[k] = __shfl_xor(m10[k], ofs);
#pragma unroll
      for (int k = 0; k < 10; k++) ins10(m10, o[k]);
    }
    if (lane == 0) {
      int b = blockIdx.x;
      blk_sumv[b] = redf[0][0] + redf[0][1] + redf[0][2] + redf[0][3];
      blk_sump[b] = redf[1][0] + redf[1][1] + redf[1][2] + redf[1][3];
      blk_cntv[b] = redu[0][0] + redu[0][1] + redu[0][2] + redu[0][3];
      blk_cntp[b] = redu[1][0] + redu[1][1] + redu[1][2] + redu[1][3];
      blk_zero[b] = redu[2][0] + redu[2][1] + redu[2][2] + redu[2][3];
#pragma unroll
      for (int k = 0; k < 10; k++) top10g[b * 10 + k] = m10[k];
    }
  }
  __syncthreads();

  // ---- decoupled last-block finalize ----
  if (tid == 0) {
    __threadfence();  // release our slots/top10g writes device-wide
    unsigned old = atomicAdd(done, 1u);
    lastFlag = (old == NBLK - 1);
  }
  __syncthreads();
  if (!lastFlag) return;
  __threadfence();  // acquire: invalidate L1, see all blocks' writes

  // stats over 528 slot rows (max 3 iters/thread, coalesced)
  float sv = 0.f, sp = 0.f;
  unsigned cv = 0, cp = 0, zz = 0;
  for (int b = tid; b < NBLK; b += 256) {
    sv += blk_sumv[b]; sp += blk_sump[b];
    cv += blk_cntv[b]; cp += blk_cntp[b]; zz += blk_zero[b];
  }
#pragma unroll
  for (int o = 32; o > 0; o >>= 1) {
    sv += __shfl_down(sv, o);
    sp += __shfl_down(sp, o);
    cv += __shfl_down(cv, o);
    cp += __shfl_down(cp, o);
    zz += __shfl_down(zz, o);
  }
  if (lane == 0) {
    redf[0][wave] = sv; redf[1][wave] = sp;
    redu[0][wave] = cv; redu[1][wave] = cp; redu[2][wave] = zz;
  }

  // top-10 over 5280 published floats (21 iters/thread, coalesced)
  float f10[10];
#pragma unroll
  for (int k = 0; k < 10; k++) f10[k] = SENT;
  for (int g = tid; g < NBLK * 10; g += 256) ins10(f10, top10g[g]);
  wave_merge10(f10);
  if (lane == 0)
#pragma unroll
    for (int k = 0; k < 10; k++) wt[wave][k] = f10[k];
  __syncthreads();

  if (tid == 0) {
    float m10[10];
#pragma unroll
    for (int k = 0; k < 10; k++) m10[k] = wt[0][k];
#pragma unroll
    for (int w = 1; w < 4; w++)
#pragma unroll
      for (int k = 0; k < 10; k++) ins10(m10, wt[w][k]);
    float topsum = 0.f;
#pragma unroll
    for (int k = 0; k < 10; k++) topsum += m10[k];
    float tsv = redf[0][0] + redf[0][1] + redf[0][2] + redf[0][3];
    float tsp = redf[1][0] + redf[1][1] + redf[1][2] + redf[1][3];
    unsigned tcv = redu[0][0] + redu[0][1] + redu[0][2] + redu[0][3];
    unsigned tcp = redu[1][0] + redu[1][1] + redu[1][2] + redu[1][3];
    unsigned tzz = redu[2][0] + redu[2][1] + redu[2][2] + redu[2][3];
    // full-matrix multiset = upper-triangle doubled: top-20 mean == top-10 mean,
    // counts double in numerator and denominator (cancel in means)
    out[0] = topsum * 0.1f;
    out[1] = (float)(2u * tzz);
    out[2] = tsp / (float)tcp;
    out[3] = (tsv - tsp) / (float)(tcv - tcp);
  }
}

extern "C" void kernel_launch(void* const* d_in, const int* in_sizes, int n_in,
                              void* d_out, int out_size, void* d_ws, size_t ws_size,
                              hipStream_t stream) {
  const float* X = (const float*)d_in[0];
  const int* tgt = (const int*)d_in[1];
  float* out = (float*)d_out;
  char* ws = (char*)d_ws;

  float* slots = (float*)ws;
  float* top10g = (float*)(ws + TOP10_OFF);
  unsigned* done = (unsigned*)(ws + DONE_OFF);
  _Float16* Xh = (_Float16*)(ws + XH_OFF);

  prep_kernel<<<(N * D / 4) / 256, 256, 0, stream>>>((const float4*)X,
                                                     (ushort4*)Xh, done);
  gemm_stats_kernel<<<NBLK, 256, 0, stream>>>(Xh, tgt, slots, top10g, done, out);
}

// Round 9
// 108.064 us; speedup vs baseline: 1.0753x; 1.0753x over previous
//
#include <hip/hip_runtime.h>
#include <hip/hip_fp16.h>

// Problem constants (fixed by the reference setup)
constexpr int N = 4096;
constexpr int D = 512;
constexpr int NT = 64;                   // 4096 / 64 tile-rows
constexpr int NBLK = NT * (NT + 1) / 2;  // 2080 upper-triangle tiles
constexpr int NSEG = 32;                 // finalize segments
constexpr int SEGSZ = NBLK / NSEG;       // 65 blocks per segment
constexpr float SENT = -1e30f;           // sentinel (invalid sites / empty slots)

typedef _Float16 f16x8 __attribute__((ext_vector_type(8)));
typedef float f32x4 __attribute__((ext_vector_type(4)));

// async 16B/lane global->LDS (wave-uniform LDS base + lane*16)
__device__ __forceinline__ void load_lds16(const _Float16* g, _Float16* l) {
  __builtin_amdgcn_global_load_lds(
      (const __attribute__((address_space(1))) void*)g,
      (__attribute__((address_space(3))) void*)l, 16, 0, 0);
}

// Exact wave top-10 by repeated selection over per-lane register candidates.
// out[r] ends up wave-uniform. Duplicates preserved (leader pops ONE copy).
template <int M>
__device__ __forceinline__ void wave_sel10(float (&vals)[M], float (&out)[10]) {
  int lane = threadIdx.x & 63;
  float lm = vals[0];
#pragma unroll
  for (int k = 1; k < M; k++) lm = fmaxf(lm, vals[k]);
#pragma unroll
  for (int r = 0; r < 10; r++) {
    float wmx = lm;
#pragma unroll
    for (int ofs = 1; ofs < 64; ofs <<= 1)
      wmx = fmaxf(wmx, __shfl_xor(wmx, ofs));
    out[r] = wmx;
    unsigned long long b = __ballot(lm == wmx);
    int leader = __ffsll(b) - 1;
    if (lane == leader) {
      bool found = false;
#pragma unroll
      for (int k = 0; k < M; k++) {
        bool hit = !found && (vals[k] == wmx);
        vals[k] = hit ? SENT : vals[k];
        found = found || hit;
      }
      lm = vals[0];
#pragma unroll
      for (int k = 1; k < M; k++) lm = fmaxf(lm, vals[k]);
    }
  }
}

// ws layout:
//   ws+0        f32 blk_sumv[2080]; f32 blk_sump[2080];
//               u32 blk_cntv[2080]; u32 blk_cntp[2080]; u32 blk_zero[2080]
//   ws+41600    f32 top10g[2080*10]
//   ws+124800   f32 statsL2[5*32]
//   ws+125440   f32 t10L2[320]
//   ws+126720   u32 done2           (zeroed by prep)
//   ws+126976   f16 Xh[N*D]
constexpr int TOP10G_OFF = 41600;
constexpr int STATSL2_OFF = 124800;
constexpr int T10L2_OFF = 125440;
constexpr int DONE2_OFF = 126720;
constexpr int XH_OFF = 126976;

// ---------------- K0: fp32 -> f16 convert (+ zero done2) ----------------
__global__ void prep_kernel(const float4* __restrict__ X4,
                            ushort4* __restrict__ Xh4,
                            unsigned* __restrict__ done2) {
  int gid = blockIdx.x * 256 + threadIdx.x;  // grid exactly N*D/4 threads
  if (gid == 0) *done2 = 0u;
  float4 v = X4[gid];
  ushort4 o;
  o.x = __half_as_ushort(__float2half_rn(v.x));
  o.y = __half_as_ushort(__float2half_rn(v.y));
  o.z = __half_as_ushort(__float2half_rn(v.z));
  o.w = __half_as_ushort(__float2half_rn(v.w));
  Xh4[gid] = o;
}

// ---------------- K1: 64x64-tile X*X^T + fused loss + selection top-10 ----------------
// Small blocks: 2080 of them, 16 KB LDS, launch_bounds(256,4) -> 4 blocks/CU
// resident (16 waves/CU). XOR swizzle: LDS pos p of row r holds chunk p^(r&7).
__global__ __launch_bounds__(256, 4) void gemm_stats_kernel(
    const _Float16* __restrict__ Xh, const int* __restrict__ tgt,
    float* __restrict__ slots, float* __restrict__ top10g) {
  float* blk_sumv = slots;
  float* blk_sump = slots + NBLK;
  unsigned* blk_cntv = (unsigned*)(slots + 2 * NBLK);
  unsigned* blk_cntp = (unsigned*)(slots + 3 * NBLK);
  unsigned* blk_zero = (unsigned*)(slots + 4 * NBLK);

  __shared__ _Float16 As[64 * 64];  // 8 KB
  __shared__ _Float16 Bs[64 * 64];  // 8 KB
  __shared__ int tA[64], tB[64];
  __shared__ float redf[2][4];
  __shared__ unsigned redu[3][4];
  __shared__ float wml[40];  // 4 waves x 10 top values

  int tid = threadIdx.x;

  // decode upper-triangle tile (br <= bc)
  int id = blockIdx.x, br = 0;
  while (id >= (NT - br)) { id -= (NT - br); br++; }
  int bc = br + id;

  if (tid < 64) tA[tid] = tgt[br * 64 + tid];
  else if (tid < 128) tB[tid - 64] = tgt[bc * 64 + (tid - 64)];

  int lane = tid & 63, wave = tid >> 6;
  int wm = (wave >> 1) << 5;  // wave's 32-row quadrant
  int wn = (wave & 1) << 5;   // wave's 32-col quadrant
  int lrow = lane & 15;
  int q4 = lane >> 4;  // quad 0..3
  int x7 = lrow & 7;   // swizzle key for ds_read side
  int quad4 = q4 * 4;

  // staging: issue i (0..1) covers chunks C=(i*4+wave)*64+lane (512 chunks);
  // row=C>>3, lds pos p=C&7 holds global chunk p^(row&7)
  int srow[2], scol[2], sdst[2];
#pragma unroll
  for (int i = 0; i < 2; i++) {
    int C = (i * 4 + wave) * 64 + lane;
    int row = C >> 3, p = C & 7;
    srow[i] = row;
    scol[i] = (p ^ (row & 7)) * 8;
    sdst[i] = (i * 4 + wave) * 512;
  }
  const _Float16* Arow = Xh + (size_t)(br * 64) * D;
  const _Float16* Brow = Xh + (size_t)(bc * 64) * D;

  f32x4 acc[2][2] = {};

  for (int k0 = 0; k0 < D; k0 += 64) {
    __syncthreads();  // previous compute done before LDS overwrite
#pragma unroll
    for (int i = 0; i < 2; i++) {
      load_lds16(Arow + srow[i] * D + k0 + scol[i], As + sdst[i]);
      load_lds16(Brow + srow[i] * D + k0 + scol[i], Bs + sdst[i]);
    }
    __syncthreads();  // compiler drains vmcnt before barrier: deposits visible
#pragma unroll
    for (int ks = 0; ks < 64; ks += 32) {
      int c0 = ks >> 3;
      f16x8 af[2], bf[2];
#pragma unroll
      for (int mi = 0; mi < 2; mi++)
        af[mi] = *(const f16x8*)&As[(wm + mi * 16 + lrow) * 64 +
                                    ((c0 + q4) ^ x7) * 8];
#pragma unroll
      for (int ni = 0; ni < 2; ni++)
        bf[ni] = *(const f16x8*)&Bs[(wn + ni * 16 + lrow) * 64 +
                                    ((c0 + q4) ^ x7) * 8];
#pragma unroll
      for (int mi = 0; mi < 2; mi++)
#pragma unroll
        for (int ni = 0; ni < 2; ni++)
          acc[mi][ni] = __builtin_amdgcn_mfma_f32_16x16x32_f16(
              af[mi], bf[ni], acc[mi][ni], 0, 0, 0);
    }
  }

  // ---- fused epilogue: masks, hinge, stats, 16 values per thread ----
  int ti2[2][4], tj2[2];
#pragma unroll
  for (int ni = 0; ni < 2; ni++) tj2[ni] = tB[wn + ni * 16 + lrow];
#pragma unroll
  for (int mi = 0; mi < 2; mi++)
#pragma unroll
    for (int r = 0; r < 4; r++) ti2[mi][r] = tA[wm + mi * 16 + quad4 + r];

  float lsv = 0.f, lsp = 0.f;
  unsigned lcv = 0, lcp = 0, lz = 0;
  int ibase = br * 64 + wm + quad4;
  int jbase = bc * 64 + wn + lrow;

  float vals[16];
#pragma unroll
  for (int mi = 0; mi < 2; mi++)
#pragma unroll
    for (int ni = 0; ni < 2; ni++)
#pragma unroll
      for (int r = 0; r < 4; r++) {
        float s = acc[mi][ni][r];
        int i = ibase + mi * 16 + r;
        int j = jbase + ni * 16;
        bool valid = j > i;  // strict upper triangle; results doubled at the end
        bool pos = valid && (ti2[mi][r] == tj2[ni]);
        float t = pos ? -s : s;
        float loss = fmaxf(0.5f + t, 0.0f);
        if (valid) { lsv += s; lcv++; if (loss == 0.0f) lz++; }
        if (pos) { lsp += s; lcp++; }
        vals[(mi * 2 + ni) * 4 + r] = valid ? loss : SENT;
      }

  // stats: wave shuffle reduce
#pragma unroll
  for (int o = 32; o > 0; o >>= 1) {
    lsv += __shfl_down(lsv, o);
    lsp += __shfl_down(lsp, o);
    lcv += __shfl_down(lcv, o);
    lcp += __shfl_down(lcp, o);
    lz  += __shfl_down(lz, o);
  }
  if (lane == 0) {
    redf[0][wave] = lsv; redf[1][wave] = lsp;
    redu[0][wave] = lcv; redu[1][wave] = lcp; redu[2][wave] = lz;
  }

  // top-10: wave selection (cheap), publish per-wave lists to LDS
  float wl[10];
  wave_sel10<16>(vals, wl);
  if (lane == 0) {
#pragma unroll
    for (int r = 0; r < 10; r++) wml[wave * 10 + r] = wl[r];
  }
  __syncthreads();

  // wave 0: merge 4 lists (40 values, one per lane for lane<40)
  if (wave == 0) {
    float mv[1];
    mv[0] = (lane < 40) ? wml[lane] : SENT;
    float b10[10];
    wave_sel10<1>(mv, b10);
    if (lane == 0) {
      int b = blockIdx.x;
      blk_sumv[b] = redf[0][0] + redf[0][1] + redf[0][2] + redf[0][3];
      blk_sump[b] = redf[1][0] + redf[1][1] + redf[1][2] + redf[1][3];
      blk_cntv[b] = redu[0][0] + redu[0][1] + redu[0][2] + redu[0][3];
      blk_cntp[b] = redu[1][0] + redu[1][1] + redu[1][2] + redu[1][3];
      blk_zero[b] = redu[2][0] + redu[2][1] + redu[2][2] + redu[2][3];
#pragma unroll
      for (int r = 0; r < 10; r++) top10g[b * 10 + r] = b10[r];
    }
  }
}

// ---------------- K2: 32-block segment-parallel finalize + decoupled merge ----------------
__global__ __launch_bounds__(256) void finalize_kernel(
    const float* __restrict__ slots, const float* __restrict__ top10g,
    float* __restrict__ statsL2, float* __restrict__ t10L2,
    unsigned* __restrict__ done2, float* __restrict__ out) {
  const float* blk_sumv = slots;
  const float* blk_sump = slots + NBLK;
  const unsigned* blk_cntv = (const unsigned*)(slots + 2 * NBLK);
  const unsigned* blk_cntp = (const unsigned*)(slots + 3 * NBLK);
  const unsigned* blk_zero = (const unsigned*)(slots + 4 * NBLK);

  __shared__ float wml[40];
  __shared__ float redf[2][4];
  __shared__ unsigned redu[3][4];
  __shared__ int lastFlag;

  int tid = threadIdx.x;
  int lane = tid & 63, wave = tid >> 6;
  int f = blockIdx.x;

  // segment stats: rows f*65 .. f*65+64
  float sv = 0.f, sp = 0.f;
  unsigned cv = 0, cp = 0, zz = 0;
  if (tid < SEGSZ) {
    int row = f * SEGSZ + tid;
    sv = blk_sumv[row]; sp = blk_sump[row];
    cv = blk_cntv[row]; cp = blk_cntp[row]; zz = blk_zero[row];
  }
#pragma unroll
  for (int o = 32; o > 0; o >>= 1) {
    sv += __shfl_down(sv, o);
    sp += __shfl_down(sp, o);
    cv += __shfl_down(cv, o);
    cp += __shfl_down(cp, o);
    zz += __shfl_down(zz, o);
  }
  if (lane == 0) {
    redf[0][wave] = sv; redf[1][wave] = sp;
    redu[0][wave] = cv; redu[1][wave] = cp; redu[2][wave] = zz;
  }

  // segment top-10: 650 floats
  float v3[3];
#pragma unroll
  for (int k = 0; k < 3; k++) {
    int g = tid + k * 256;
    v3[k] = (g < SEGSZ * 10) ? top10g[f * SEGSZ * 10 + g] : SENT;
  }
  float wl[10];
  wave_sel10<3>(v3, wl);
  if (lane == 0) {
#pragma unroll
    for (int r = 0; r < 10; r++) wml[wave * 10 + r] = wl[r];
  }
  __syncthreads();
  if (wave == 0) {
    float mv[1];
    mv[0] = (lane < 40) ? wml[lane] : SENT;
    float s10[10];
    wave_sel10<1>(mv, s10);
    if (lane == 0) {
      statsL2[f] = redf[0][0] + redf[0][1] + redf[0][2] + redf[0][3];
      statsL2[NSEG + f] = redf[1][0] + redf[1][1] + redf[1][2] + redf[1][3];
      ((unsigned*)statsL2)[2 * NSEG + f] =
          redu[0][0] + redu[0][1] + redu[0][2] + redu[0][3];
      ((unsigned*)statsL2)[3 * NSEG + f] =
          redu[1][0] + redu[1][1] + redu[1][2] + redu[1][3];
      ((unsigned*)statsL2)[4 * NSEG + f] =
          redu[2][0] + redu[2][1] + redu[2][2] + redu[2][3];
#pragma unroll
      for (int r = 0; r < 10; r++) t10L2[f * 10 + r] = s10[r];
    }
  }
  __syncthreads();

  // decoupled final merge by the last-arriving block
  if (tid == 0) {
    __threadfence();
    unsigned old = atomicAdd(done2, 1u);
    lastFlag = (old == NSEG - 1);
  }
  __syncthreads();
  if (!lastFlag) return;
  __threadfence();

  // final stats over 32 segment rows
  float sv2 = 0.f, sp2 = 0.f;
  unsigned cv2 = 0, cp2 = 0, zz2 = 0;
  if (tid < NSEG) {
    sv2 = statsL2[tid]; sp2 = statsL2[NSEG + tid];
    cv2 = ((const unsigned*)statsL2)[2 * NSEG + tid];
    cp2 = ((const unsigned*)statsL2)[3 * NSEG + tid];
    zz2 = ((const unsigned*)statsL2)[4 * NSEG + tid];
  }
#pragma unroll
  for (int o = 32; o > 0; o >>= 1) {
    sv2 += __shfl_down(sv2, o);
    sp2 += __shfl_down(sp2, o);
    cv2 += __shfl_down(cv2, o);
    cp2 += __shfl_down(cp2, o);
    zz2 += __shfl_down(zz2, o);
  }
  if (lane == 0) {
    redf[0][wave] = sv2; redf[1][wave] = sp2;
    redu[0][wave] = cv2; redu[1][wave] = cp2; redu[2][wave] = zz2;
  }

  // final top-10 over 320 floats
  float v2[2];
  v2[0] = (tid < NSEG * 10) ? t10L2[tid] : SENT;
  int g2 = tid + 256;
  v2[1] = (g2 < NSEG * 10) ? t10L2[g2] : SENT;
  float wl2[10];
  wave_sel10<2>(v2, wl2);
  if (lane == 0) {
#pragma unroll
    for (int r = 0; r < 10; r++) wml[wave * 10 + r] = wl2[r];
  }
  __syncthreads();

  if (wave == 0) {
    float mv[1];
    mv[0] = (lane < 40) ? wml[lane] : SENT;
    float f10[10];
    wave_sel10<1>(mv, f10);
    if (lane == 0) {
      float topsum = 0.f;
#pragma unroll
      for (int r = 0; r < 10; r++) topsum += f10[r];
      float tsv = redf[0][0] + redf[0][1] + redf[0][2] + redf[0][3];
      float tsp = redf[1][0] + redf[1][1] + redf[1][2] + redf[1][3];
      unsigned tcv = redu[0][0] + redu[0][1] + redu[0][2] + redu[0][3];
      unsigned tcp = redu[1][0] + redu[1][1] + redu[1][2] + redu[1][3];
      unsigned tzz = redu[2][0] + redu[2][1] + redu[2][2] + redu[2][3];
      // full-matrix multiset = upper-triangle doubled: top-20 mean == top-10
      // mean; counts double in numerator and denominator (cancel in means)
      out[0] = topsum * 0.1f;
      out[1] = (float)(2u * tzz);
      out[2] = tsp / (float)tcp;
      out[3] = (tsv - tsp) / (float)(tcv - tcp);
    }
  }
}

extern "C" void kernel_launch(void* const* d_in, const int* in_sizes, int n_in,
                              void* d_out, int out_size, void* d_ws, size_t ws_size,
                              hipStream_t stream) {
  const float* X = (const float*)d_in[0];
  const int* tgt = (const int*)d_in[1];
  float* out = (float*)d_out;
  char* ws = (char*)d_ws;

  float* slots = (float*)ws;
  float* top10g = (float*)(ws + TOP10G_OFF);
  float* statsL2 = (float*)(ws + STATSL2_OFF);
  float* t10L2 = (float*)(ws + T10L2_OFF);
  unsigned* done2 = (unsigned*)(ws + DONE2_OFF);
  _Float16* Xh = (_Float16*)(ws + XH_OFF);

  prep_kernel<<<(N * D / 4) / 256, 256, 0, stream>>>((const float4*)X,
                                                     (ushort4*)Xh, done2);
  gemm_stats_kernel<<<NBLK, 256, 0, stream>>>(Xh, tgt, slots, top10g);
  finalize_kernel<<<NSEG, 256, 0, stream>>>(slots, top10g, statsL2, t10L2,
                                            done2, out);
}